// Round 11
// baseline (2028.274 us; speedup 1.0000x reference)
//
#include <hip/hip_runtime.h>
#include <math.h>

#define NTOK 200704          // B*S = 4096*49
#define CDIM 384
#define NH3  1152            // 3*C
#define NHEADS 12
#define HD   32
#define SEQ  49
#define QL   77070336ULL     // CDIM*NTOK (one third of T)
#define MPAD 1280            // padded M for gemm1 (1152 -> 5*256)

typedef __attribute__((ext_vector_type(8))) short short8;
typedef __attribute__((ext_vector_type(4))) float f32x4;
typedef __attribute__((ext_vector_type(16))) float f32x16;

__device__ __forceinline__ float gelu_exact(float x) {
    return 0.5f * x * (1.0f + erff(x * 0.70710678118654752f));
}
__device__ __forceinline__ unsigned bf16rn_bits(float x) {
    unsigned u = __float_as_uint(x);
    return (u + 0x7fffu + ((u >> 16) & 1u)) & 0xffff0000u;
}
__device__ __forceinline__ unsigned packsplit(float x) {
    unsigned hb = bf16rn_bits(x);
    float r = x - __uint_as_float(hb);
    unsigned lb = bf16rn_bits(r);
    return hb | (lb >> 16);
}
__device__ __forceinline__ void gl_lds16(const void* g, void* l) {
    __builtin_amdgcn_global_load_lds((const __attribute__((address_space(1))) void*)g,
                                     (__attribute__((address_space(3))) void*)l, 16, 0, 0);
}
union F8 { short8 v; unsigned u[4]; };
__device__ __forceinline__ void unpack8(uint4 a, uint4 b, short8 &h, short8 &l) {
    F8 H, L;
    H.u[0] = __builtin_amdgcn_perm(a.y, a.x, 0x07060302u);
    H.u[1] = __builtin_amdgcn_perm(a.w, a.z, 0x07060302u);
    H.u[2] = __builtin_amdgcn_perm(b.y, b.x, 0x07060302u);
    H.u[3] = __builtin_amdgcn_perm(b.w, b.z, 0x07060302u);
    L.u[0] = __builtin_amdgcn_perm(a.y, a.x, 0x05040100u);
    L.u[1] = __builtin_amdgcn_perm(a.w, a.z, 0x05040100u);
    L.u[2] = __builtin_amdgcn_perm(b.y, b.x, 0x05040100u);
    L.u[3] = __builtin_amdgcn_perm(b.w, b.z, 0x05040100u);
    h = H.v; l = L.v;
}

// ---------------------------------------------------------------------------
// prep_w: w (Kdim x Msrc row-major fp32) -> hi/lo bf16 granules [koct][Mstore][8]
// rows >= Msrc zero-padded.
// ---------------------------------------------------------------------------
__global__ __launch_bounds__(256)
void prep_w(const float* __restrict__ w, unsigned short* __restrict__ hi,
            unsigned short* __restrict__ lo, int Msrc, int Mstore, int Kdim) {
    int idx = blockIdx.x * 256 + threadIdx.x;
    int total = Mstore * (Kdim >> 3);
    if (idx >= total) return;
    int koct = idx / Mstore, m = idx - koct * Mstore;
    unsigned short h8[8], l8[8];
    #pragma unroll
    for (int j = 0; j < 8; ++j) {
        float v = (m < Msrc) ? w[(size_t)(koct * 8 + j) * Msrc + m] : 0.f;
        unsigned hb = bf16rn_bits(v);
        h8[j] = (unsigned short)(hb >> 16);
        l8[j] = (unsigned short)(bf16rn_bits(v - __uint_as_float(hb)) >> 16);
    }
    size_t o = (size_t)idx * 8;
    *(short8*)&hi[o] = *(short8*)h8;
    *(short8*)&lo[o] = *(short8*)l8;
}

// prep_x: fp32 row-major -> packed-split u32, same layout
__global__ __launch_bounds__(256)
void prep_x(const float* __restrict__ x, unsigned* __restrict__ xp, int total8) {
    int idx = blockIdx.x * 256 + threadIdx.x;
    if (idx >= total8) return;
    size_t e = (size_t)idx * 8;
    float4 v0 = *(const float4*)&x[e];
    float4 v1 = *(const float4*)&x[e + 4];
    *(uint4*)&xp[e]     = make_uint4(packsplit(v0.x), packsplit(v0.y), packsplit(v0.z), packsplit(v0.w));
    *(uint4*)&xp[e + 4] = make_uint4(packsplit(v1.x), packsplit(v1.y), packsplit(v1.z), packsplit(v1.w));
}

// ---------------------------------------------------------------------------
// gemm_ring (gemm1): tile 256x128 (M x N), BK=32 packed, 8 waves (4x2 of
// 64x64), RING of 3 LDS slots (48 KB each), depth-2 prefetch with counted
// vmcnt(6), 4 fine phases per K-tile (m201-style interleave), bf16x3.
// A = weight granules [koct][MPAD][8] hi/lo u16 (MODE1); B = packed u32
// [NTOK][K] (MODE2, slot-swizzled). Out packed u32, gelu+bias (row bias).
// ---------------------------------------------------------------------------
__global__ __launch_bounds__(512, 2)
void gemm_ring(const unsigned short* __restrict__ Agh, const unsigned short* __restrict__ Agl,
               const unsigned* __restrict__ Bp, const float* __restrict__ bias,
               unsigned* __restrict__ outP, int N, int K, int Mreal) {
    __shared__ char lds[147456] __attribute__((aligned(16)));   // 3 x 48 KB

    const int tid = threadIdx.x;
    const int wg = (blockIdx.x & 7) * 980 + (blockIdx.x >> 3);  // 7840 = 8*980
    const int mT = wg % 5, nT = wg / 5;                         // M-fast
    const int m0 = mT * 256, n0 = nT * 128;

    const int wid = tid >> 6, lane = tid & 63;
    const int wm = wid >> 1, wn = wid & 1;                      // 4 x 2 waves
    const int l31 = lane & 31, lh = lane >> 5;

    f32x16 acc[2][2] = {};                                      // [mi][ni]
    const int nK = K / 32;                                      // 12

    auto slotbase = [&](int kt) -> char* { return lds + (kt % 3) * 49152; };

    // A slot layout: [hi 16K][lo 16K]; unit g = koct*256 + r at g*16
    auto stageA = [&](int kt, int it) {
        char* b = slotbase(kt);
        int g = it * 512 + tid;
        int koct = g >> 8, r = g & 255;
        size_t src = ((size_t)(kt * 4 + koct) * MPAD + m0 + r) * 8;
        gl_lds16(Agh + src, b + g * 16);
        gl_lds16(Agl + src, b + 16384 + g * 16);
    };
    // B slot layout at +32768: unit u = row*8 + physslot at u*16;
    // logical slot L stored at physical L ^ (row&7)
    auto stageB = [&](int kt, int half) {
        char* b = slotbase(kt);
        int u = half * 512 + tid;
        int row = u >> 3, sl = u & 7;
        int swz = sl ^ (row & 7);
        gl_lds16(Bp + (size_t)(n0 + row) * K + kt * 32 + swz * 4,
                 b + 32768 + u * 16);
    };

    short8 bh[2][2], bl[2][2];   // [ni][ko], persist across phases
    auto ldB = [&](int kt, int ko) {
        const char* bB = slotbase(kt) + 32768;
        #pragma unroll
        for (int ni = 0; ni < 2; ++ni) {
            int r = wn * 64 + ni * 32 + l31;
            int o = 2 * ko + lh;
            int s0 = (2 * o) ^ (r & 7);
            const char* p = bB + r * 128;
            uint4 a = *(const uint4*)(p + s0 * 16);
            uint4 b = *(const uint4*)(p + (s0 ^ 1) * 16);
            unpack8(a, b, bh[ni][ko], bl[ni][ko]);
        }
    };

    // prologue: stage tiles 0 and 1 (6 loads each), wait tile 0 only
    stageA(0, 0); stageA(0, 1); stageB(0, 0); stageB(0, 1);
    stageA(1, 0); stageA(1, 1); stageB(1, 0); stageB(1, 1);
    asm volatile("s_waitcnt vmcnt(6)" ::: "memory");
    __builtin_amdgcn_sched_barrier(0);
    __builtin_amdgcn_s_barrier();

    for (int kt = 0; kt < nK; ++kt) {
        const char* aB = slotbase(kt);
        const bool pf = (kt + 2 < nK);
        short8 ah, al;

        #pragma unroll
        for (int ph = 0; ph < 4; ++ph) {
            const int mi = ph >> 1, ko = ph & 1;
            // ds-reads for this phase
            if (ph == 0) ldB(kt, 0);
            if (ph == 1) ldB(kt, 1);
            {
                int r = wm * 64 + mi * 32 + l31;
                int o = 2 * ko + lh;
                ah = *(const short8*)(aB + (o * 256 + r) * 16);
                al = *(const short8*)(aB + 16384 + (o * 256 + r) * 16);
            }
            // prefetch issue (2 gl_lds in ph0/ph1, 1 in ph2/ph3)
            if (pf) {
                if (ph == 0) stageA(kt + 2, 0);
                else if (ph == 1) stageA(kt + 2, 1);
                else if (ph == 2) stageB(kt + 2, 0);
                else stageB(kt + 2, 1);
            }
            __builtin_amdgcn_s_barrier();
            asm volatile("s_waitcnt lgkmcnt(0)" ::: "memory");
            __builtin_amdgcn_sched_barrier(0);
            __builtin_amdgcn_s_setprio(1);
            #pragma unroll
            for (int ni = 0; ni < 2; ++ni) {
                acc[mi][ni] = __builtin_amdgcn_mfma_f32_32x32x16_bf16(ah, bh[ni][ko], acc[mi][ni], 0, 0, 0);
                acc[mi][ni] = __builtin_amdgcn_mfma_f32_32x32x16_bf16(ah, bl[ni][ko], acc[mi][ni], 0, 0, 0);
                acc[mi][ni] = __builtin_amdgcn_mfma_f32_32x32x16_bf16(al, bh[ni][ko], acc[mi][ni], 0, 0, 0);
            }
            __builtin_amdgcn_s_setprio(0);
            if (ph == 3 && kt < nK - 1) {
                // K-tile boundary: counted wait (never 0 while prefetching)
                if (pf) asm volatile("s_waitcnt vmcnt(6)" ::: "memory");
                else    asm volatile("s_waitcnt vmcnt(0)" ::: "memory");
                __builtin_amdgcn_sched_barrier(0);
            }
            __builtin_amdgcn_s_barrier();
        }
    }

    // epilogue: gelu(acc + bias[row]) -> packed u32, guard padded rows
    #pragma unroll
    for (int mi = 0; mi < 2; ++mi) {
        #pragma unroll
        for (int ni = 0; ni < 2; ++ni) {
            int gc = n0 + wn * 64 + ni * 32 + l31;
            #pragma unroll
            for (int reg = 0; reg < 16; ++reg) {
                int gr = m0 + wm * 64 + mi * 32 + (reg & 3) + 8 * (reg >> 2) + 4 * lh;
                if (gr < Mreal) {
                    float v = gelu_exact(acc[mi][ni][reg] + bias[gr]);
                    outP[(size_t)gr * N + gc] = packsplit(v);
                }
            }
        }
    }
}

// ---------------------------------------------------------------------------
// gemm_b3 (g3/g4 + fallback): 128x128 tile, BK=32, 4 waves (2x2 of 64x64),
// single-buffered LDS, MFMA 32x32x16. (R8-proven)
// ---------------------------------------------------------------------------
template<int AMODE, int BMODE, bool BIAS_ROW, bool OUTF>
__global__ __launch_bounds__(256, 4)
void gemm_b3(const float* __restrict__ Af,
             const unsigned short* __restrict__ Agh, const unsigned short* __restrict__ Agl,
             const unsigned* __restrict__ Ap,
             const float* __restrict__ Bf,
             const unsigned short* __restrict__ Bgh, const unsigned short* __restrict__ Bgl,
             const unsigned* __restrict__ Bp,
             const float* __restrict__ bias, float* __restrict__ outF,
             unsigned* __restrict__ outP,
             int M, int N, int K, int nMt, int cpx) {
    __shared__ char smA[16384];
    __shared__ char smB[16384];
    const int tid = threadIdx.x;
    int m0, n0;
    if (cpx > 0) {
        int wg = (blockIdx.x & 7) * cpx + (blockIdx.x >> 3);
        m0 = (wg % nMt) * 128;
        n0 = (wg / nMt) * 128;
    } else {
        n0 = blockIdx.x * 128;
        m0 = blockIdx.y * 128;
    }
    const int wid = tid >> 6, lane = tid & 63;
    const int wm = wid >> 1, wn = wid & 1;
    const int l31 = lane & 31, lh = lane >> 5;
    const int f_r = tid >> 3, f_f4 = tid & 7;
    const int f_qq = f_f4 >> 1, f_half = (f_f4 & 1) * 8;

    unsigned short* BhT = (unsigned short*)smB;
    unsigned short* BlT = (unsigned short*)(smB + 8192);

    f32x16 acc[2][2] = {};

    for (int k0 = 0; k0 < K; k0 += 32) {
        const int kb = k0 >> 3;
        if constexpr (AMODE == 1) {
            #pragma unroll
            for (int it = 0; it < 2; ++it) {
                int g = it * 256 + tid;
                int qq = g >> 7, r = g & 127;
                size_t src = ((size_t)(kb + qq) * M + m0 + r) * 8;
                gl_lds16(Agh + src, smA + g * 16);
                gl_lds16(Agl + src, smA + 8192 + g * 16);
            }
        } else if constexpr (AMODE == 2) {
            #pragma unroll
            for (int it = 0; it < 4; ++it) {
                int row = it * 32 + (tid >> 3);
                int slot = (tid & 7) ^ (row & 7);
                gl_lds16(Ap + (size_t)(m0 + row) * K + k0 + slot * 4,
                         smA + (size_t)(it * 256 + tid) * 16);
            }
        }
        if constexpr (BMODE == 1) {
            #pragma unroll
            for (int it = 0; it < 2; ++it) {
                int g = it * 256 + tid;
                int qq = g >> 7, r = g & 127;
                size_t src = ((size_t)(kb + qq) * N + n0 + r) * 8;
                gl_lds16(Bgh + src, smB + g * 16);
                gl_lds16(Bgl + src, smB + 8192 + g * 16);
            }
        } else if constexpr (BMODE == 2) {
            #pragma unroll
            for (int it = 0; it < 4; ++it) {
                int row = it * 32 + (tid >> 3);
                int slot = (tid & 7) ^ (row & 7);
                gl_lds16(Bp + (size_t)(n0 + row) * K + k0 + slot * 4,
                         smB + (size_t)(it * 256 + tid) * 16);
            }
        } else {
            #pragma unroll
            for (int it = 0; it < 4; ++it) {
                int r = it * 32 + f_r;
                float4 v = *(const float4*)&Bf[(size_t)(n0 + r) * K + k0 + f_f4 * 4];
                unsigned hb0 = bf16rn_bits(v.x), hb1 = bf16rn_bits(v.y);
                unsigned hb2 = bf16rn_bits(v.z), hb3 = bf16rn_bits(v.w);
                unsigned l0 = bf16rn_bits(v.x - __uint_as_float(hb0)) >> 16;
                unsigned l1 = bf16rn_bits(v.y - __uint_as_float(hb1)) >> 16;
                unsigned l2 = bf16rn_bits(v.z - __uint_as_float(hb2)) >> 16;
                unsigned l3 = bf16rn_bits(v.w - __uint_as_float(hb3)) >> 16;
                unsigned h0 = hb0 >> 16, h1 = hb1 >> 16, h2 = hb2 >> 16, h3 = hb3 >> 16;
                *(uint2*)((char*)(BhT + (f_qq * 128 + r) * 8) + f_half) =
                    make_uint2(h0 | (h1 << 16), h2 | (h3 << 16));
                *(uint2*)((char*)(BlT + (f_qq * 128 + r) * 8) + f_half) =
                    make_uint2(l0 | (l1 << 16), l2 | (l3 << 16));
            }
        }
        __syncthreads();

        short8 ah[2][2], al[2][2], bh[2][2], bl[2][2];
        #pragma unroll
        for (int mi = 0; mi < 2; ++mi) {
            int r = wm * 64 + mi * 32 + l31;
            #pragma unroll
            for (int ko = 0; ko < 2; ++ko) {
                int o = 2 * ko + lh;
                if constexpr (AMODE == 2) {
                    int s0 = (2 * o) ^ (r & 7), s1 = s0 ^ 1;
                    const unsigned* base = (const unsigned*)smA + r * 32;
                    uint4 a = *(const uint4*)(base + s0 * 4);
                    uint4 b = *(const uint4*)(base + s1 * 4);
                    unpack8(a, b, ah[mi][ko], al[mi][ko]);
                } else {
                    ah[mi][ko] = *(const short8*)((const unsigned short*)smA + (o * 128 + r) * 8);
                    al[mi][ko] = *(const short8*)((const unsigned short*)(smA + 8192) + (o * 128 + r) * 8);
                }
            }
        }
        #pragma unroll
        for (int ni = 0; ni < 2; ++ni) {
            int r = wn * 64 + ni * 32 + l31;
            #pragma unroll
            for (int ko = 0; ko < 2; ++ko) {
                int o = 2 * ko + lh;
                if constexpr (BMODE == 2) {
                    int s0 = (2 * o) ^ (r & 7), s1 = s0 ^ 1;
                    const unsigned* base = (const unsigned*)smB + r * 32;
                    uint4 a = *(const uint4*)(base + s0 * 4);
                    uint4 b = *(const uint4*)(base + s1 * 4);
                    unpack8(a, b, bh[ni][ko], bl[ni][ko]);
                } else {
                    bh[ni][ko] = *(const short8*)(BhT + (o * 128 + r) * 8);
                    bl[ni][ko] = *(const short8*)(BlT + (o * 128 + r) * 8);
                }
            }
        }
        #pragma unroll
        for (int ko = 0; ko < 2; ++ko)
            #pragma unroll
            for (int mi = 0; mi < 2; ++mi)
                #pragma unroll
                for (int ni = 0; ni < 2; ++ni) {
                    acc[mi][ni] = __builtin_amdgcn_mfma_f32_32x32x16_bf16(ah[mi][ko], bh[ni][ko], acc[mi][ni], 0, 0, 0);
                    acc[mi][ni] = __builtin_amdgcn_mfma_f32_32x32x16_bf16(ah[mi][ko], bl[ni][ko], acc[mi][ni], 0, 0, 0);
                    acc[mi][ni] = __builtin_amdgcn_mfma_f32_32x32x16_bf16(al[mi][ko], bh[ni][ko], acc[mi][ni], 0, 0, 0);
                }
        __syncthreads();
    }

    #pragma unroll
    for (int mi = 0; mi < 2; ++mi) {
        #pragma unroll
        for (int ni = 0; ni < 2; ++ni) {
            int gc = n0 + wn * 64 + ni * 32 + l31;
            #pragma unroll
            for (int reg = 0; reg < 16; ++reg) {
                int gr = m0 + wm * 64 + mi * 32 + (reg & 3) + 8 * (reg >> 2) + 4 * lh;
                float b = BIAS_ROW ? bias[gr] : bias[gc];
                float v = gelu_exact(acc[mi][ni][reg] + b);
                if constexpr (OUTF) outF[(size_t)gr * N + gc] = v;
                else                outP[(size_t)gr * N + gc] = packsplit(v);
            }
        }
    }
}

// ---------------------------------------------------------------------------
// MFMA attention (R10-proven): one wave per (window, head), no block
// barriers (wave-private LDS), b64 V^T staging.
// ---------------------------------------------------------------------------
__global__ __launch_bounds__(256, 2)
void attn_mfma(const unsigned* __restrict__ Tp, const float* __restrict__ bias_table,
               unsigned* __restrict__ Yp) {
    __shared__ unsigned short Vh[4][32][72];
    __shared__ unsigned short Vl[4][32][72];
    __shared__ unsigned PHs[4][16][36];
    __shared__ unsigned PLs[4][16][36];

    const int tid = threadIdx.x, wid = tid >> 6, lane = tid & 63;
    const int pidx = blockIdx.x * 4 + wid;
    const int b2 = pidx / NHEADS, h = pidx - b2 * NHEADS;
    const size_t qoff = (size_t)b2 * 18816 + (size_t)h * 1568;
    const int r15 = lane & 15, g = lane >> 4;

    #pragma unroll
    for (int it = 0; it < 2; ++it) {
        const int dq = lane & 7;
        const int tq = (lane >> 3) + it * 8;
        uint4 p[4];
        #pragma unroll
        for (int u = 0; u < 4; ++u) {
            int t = tq * 4 + u; if (t > 48) t = 48;
            p[u] = *(const uint4*)&Tp[2 * QL + qoff + (size_t)t * HD + dq * 4];
        }
        #pragma unroll
        for (int c = 0; c < 4; ++c) {
            unsigned q0 = (c == 0) ? p[0].x : (c == 1) ? p[0].y : (c == 2) ? p[0].z : p[0].w;
            unsigned q1 = (c == 0) ? p[1].x : (c == 1) ? p[1].y : (c == 2) ? p[1].z : p[1].w;
            unsigned q2 = (c == 0) ? p[2].x : (c == 1) ? p[2].y : (c == 2) ? p[2].z : p[2].w;
            unsigned q3 = (c == 0) ? p[3].x : (c == 1) ? p[3].y : (c == 2) ? p[3].z : p[3].w;
            unsigned hw0 = __builtin_amdgcn_perm(q1, q0, 0x07060302u);
            unsigned hw1 = __builtin_amdgcn_perm(q3, q2, 0x07060302u);
            unsigned lw0 = __builtin_amdgcn_perm(q1, q0, 0x05040100u);
            unsigned lw1 = __builtin_amdgcn_perm(q3, q2, 0x05040100u);
            *(uint2*)&Vh[wid][dq * 4 + c][tq * 4] = make_uint2(hw0, hw1);
            *(uint2*)&Vl[wid][dq * 4 + c][tq * 4] = make_uint2(lw0, lw1);
        }
    }

    f32x4 S[4][4];
    int cS[4];
    #pragma unroll
    for (int st = 0; st < 4; ++st) {
        int s = st * 16 + r15; if (s > 48) s = 48;
        int sd = (s * 37) >> 8;
        cS[st] = 156 * (12 - (s - 6 * sd)) + h;
    }
    #pragma unroll
    for (int tt = 0; tt < 4; ++tt)
        #pragma unroll
        for (int r = 0; r < 4; ++r) {
            int t = tt * 16 + 4 * g + r; int tc2 = t > 48 ? 48 : t;
            int td = (tc2 * 37) >> 8;
            int at = 156 * (tc2 - 6 * td);
            #pragma unroll
            for (int st = 0; st < 4; ++st)
                S[tt][st][r] = bias_table[at + cS[st]];
        }

    short8 qh[4], qlo[4];
    #pragma unroll
    for (int st = 0; st < 4; ++st) {
        int s = st * 16 + r15; if (s > 48) s = 48;
        const unsigned* p = Tp + qoff + (size_t)s * HD + g * 8;
        uint4 a = *(const uint4*)p;
        uint4 b = *(const uint4*)(p + 4);
        unpack8(a, b, qh[st], qlo[st]);
    }
    #pragma unroll
    for (int tt = 0; tt < 4; ++tt) {
        int t = tt * 16 + r15; if (t > 48) t = 48;
        const unsigned* p = Tp + QL + qoff + (size_t)t * HD + g * 8;
        uint4 a = *(const uint4*)p;
        uint4 b = *(const uint4*)(p + 4);
        short8 kh, kl; unpack8(a, b, kh, kl);
        #pragma unroll
        for (int st = 0; st < 4; ++st) {
            S[tt][st] = __builtin_amdgcn_mfma_f32_16x16x32_bf16(kh, qh[st],  S[tt][st], 0, 0, 0);
            S[tt][st] = __builtin_amdgcn_mfma_f32_16x16x32_bf16(kh, qlo[st], S[tt][st], 0, 0, 0);
            S[tt][st] = __builtin_amdgcn_mfma_f32_16x16x32_bf16(kl, qh[st],  S[tt][st], 0, 0, 0);
        }
    }
    #pragma unroll
    for (int st = 0; st < 4; ++st) {
        S[3][st][0] = (g == 0) ? S[3][st][0] : -1e30f;
        S[3][st][1] = -1e30f; S[3][st][2] = -1e30f; S[3][st][3] = -1e30f;
    }
    float inv[4];
    #pragma unroll
    for (int st = 0; st < 4; ++st) {
        float mx = -1e30f;
        #pragma unroll
        for (int tt = 0; tt < 4; ++tt)
            #pragma unroll
            for (int r = 0; r < 4; ++r) mx = fmaxf(mx, S[tt][st][r]);
        mx = fmaxf(mx, __shfl_xor(mx, 16));
        mx = fmaxf(mx, __shfl_xor(mx, 32));
        float sm = 0.f;
        #pragma unroll
        for (int tt = 0; tt < 4; ++tt)
            #pragma unroll
            for (int r = 0; r < 4; ++r) {
                float e = __expf(S[tt][st][r] - mx);
                S[tt][st][r] = e; sm += e;
            }
        sm += __shfl_xor(sm, 16);
        sm += __shfl_xor(sm, 32);
        inv[st] = 1.0f / sm;
    }
    short8 vfh[2][2], vfl[2][2];
    #pragma unroll
    for (int dt = 0; dt < 2; ++dt)
        #pragma unroll
        for (int kc = 0; kc < 2; ++kc) {
            int d = dt * 16 + r15;
            vfh[dt][kc] = *(const short8*)&Vh[wid][d][kc * 32 + g * 8];
            vfl[dt][kc] = *(const short8*)&Vl[wid][d][kc * 32 + g * 8];
        }
    for (int st = 0; st < 4; ++st) {
        #pragma unroll
        for (int tt = 0; tt < 4; ++tt)
            #pragma unroll
            for (int rp = 0; rp < 2; ++rp) {
                float p0 = S[tt][st][2 * rp]     * inv[st];
                float p1 = S[tt][st][2 * rp + 1] * inv[st];
                unsigned h0 = bf16rn_bits(p0), h1 = bf16rn_bits(p1);
                unsigned l0 = bf16rn_bits(p0 - __uint_as_float(h0));
                unsigned l1 = bf16rn_bits(p1 - __uint_as_float(h1));
                int w = tt * 8 + 2 * g + rp;
                int wsw = (((w >> 2) ^ (r15 & 7)) << 2) + (w & 3);
                PHs[wid][r15][wsw] = __builtin_amdgcn_perm(h1, h0, 0x07060302u);
                PLs[wid][r15][wsw] = __builtin_amdgcn_perm(l1, l0, 0x07060302u);
            }
        f32x4 o[2] = {};
        #pragma unroll
        for (int kc = 0; kc < 2; ++kc) {
            int grp = (4 * kc + g) ^ (r15 & 7);
            short8 ph = *(const short8*)&PHs[wid][r15][grp * 4];
            short8 pl = *(const short8*)&PLs[wid][r15][grp * 4];
            #pragma unroll
            for (int dt = 0; dt < 2; ++dt) {
                o[dt] = __builtin_amdgcn_mfma_f32_16x16x32_bf16(ph, vfh[dt][kc], o[dt], 0, 0, 0);
                o[dt] = __builtin_amdgcn_mfma_f32_16x16x32_bf16(ph, vfl[dt][kc], o[dt], 0, 0, 0);
                o[dt] = __builtin_amdgcn_mfma_f32_16x16x32_bf16(pl, vfh[dt][kc], o[dt], 0, 0, 0);
            }
        }
        #pragma unroll
        for (int r = 0; r < 4; ++r) {
            int s = st * 16 + 4 * g + r;
            if (s < SEQ) {
                size_t ob = ((size_t)b2 * SEQ + s) * CDIM + h * HD + r15;
                Yp[ob]      = packsplit(o[0][r]);
                Yp[ob + 16] = packsplit(o[1][r]);
            }
        }
    }
}

extern "C" void kernel_launch(void* const* d_in, const int* in_sizes, int n_in,
                              void* d_out, int out_size, void* d_ws, size_t ws_size,
                              hipStream_t stream) {
    const float* x          = (const float*)d_in[0];
    const float* w_qkv      = (const float*)d_in[1];
    const float* b_qkv      = (const float*)d_in[2];
    const float* bias_table = (const float*)d_in[3];
    const float* w_out      = (const float*)d_in[4];
    const float* b_out      = (const float*)d_in[5];
    unsigned* Tp = (unsigned*)d_ws;
    const size_t TPW = 3 * QL;

    const size_t WQG = 48ULL * MPAD * 8;     // u16 per wq granule array (padded)
    const size_t WOG = 48ULL * CDIM * 8;
    const size_t need = TPW * 4ULL + 2 * WQG * 2ULL + 2 * WOG * 2ULL;

    if (ws_size >= need) {
        unsigned short* wq_hi = (unsigned short*)((char*)d_ws + TPW * 4ULL);
        unsigned short* wq_lo = wq_hi + WQG;
        unsigned short* wo_hi = wq_lo + WQG;
        unsigned short* wo_lo = wo_hi + WOG;
        unsigned* xp = (unsigned*)d_out;

        prep_w<<<(MPAD * 48 + 255) / 256, 256, 0, stream>>>(w_qkv, wq_hi, wq_lo, NH3, MPAD, CDIM);
        prep_w<<<(CDIM * 48 + 255) / 256, 256, 0, stream>>>(w_out, wo_hi, wo_lo, CDIM, CDIM, CDIM);
        prep_x<<<(NTOK * CDIM / 8 + 255) / 256, 256, 0, stream>>>(x, xp, NTOK * CDIM / 8);

        // 1) T = gelu(wq^T @ x^T + b_qkv): ring-3 deep pipeline, grid 5*1568
        gemm_ring<<<7840, 512, 0, stream>>>(wq_hi, wq_lo, xp, b_qkv, Tp, NTOK, CDIM, NH3);

        // 2) attention -> Y0 packed in d_out
        attn_mfma<<<12288, 256, 0, stream>>>(Tp, bias_table, (unsigned*)d_out);

        // 3) Y1 = gelu(Y0 @ wout + b_out) -> Tp (packed)
        gemm_b3<2, 1, false, false><<<dim3(3, 1568), 256, 0, stream>>>(
            nullptr, nullptr, nullptr, (unsigned*)d_out, nullptr, wo_hi, wo_lo, nullptr,
            b_out, nullptr, Tp, NTOK, CDIM, CDIM, 0, 0);

        // 4) out = gelu(Y1 @ wout + b_out)
        gemm_b3<2, 1, false, true><<<dim3(3, 1568), 256, 0, stream>>>(
            nullptr, nullptr, nullptr, Tp, nullptr, wo_hi, wo_lo, nullptr,
            b_out, (float*)d_out, nullptr, NTOK, CDIM, CDIM, 0, 0);
    } else {
        // fallback: weights in d_out / dead T third; x staged fp32 inline
        unsigned short* wq_hi = (unsigned short*)d_out;
        unsigned short* wq_lo = wq_hi + (size_t)NH3 * CDIM;
        unsigned short* wo_hi = (unsigned short*)(Tp + QL);
        unsigned short* wo_lo = wo_hi + (size_t)CDIM * CDIM;

        prep_w<<<(NH3 * 48 + 255) / 256, 256, 0, stream>>>(w_qkv, wq_hi, wq_lo, NH3, NH3, CDIM);

        gemm_b3<1, 0, true, false><<<14112, 256, 0, stream>>>(
            nullptr, wq_hi, wq_lo, nullptr, x, nullptr, nullptr, nullptr,
            b_qkv, nullptr, Tp, NH3, NTOK, CDIM, 9, 1764);

        attn_mfma<<<12288, 256, 0, stream>>>(Tp, bias_table, (unsigned*)d_out);

        prep_w<<<(CDIM * 48 + 255) / 256, 256, 0, stream>>>(w_out, wo_hi, wo_lo, CDIM, CDIM, CDIM);

        gemm_b3<2, 1, false, false><<<dim3(3, 1568), 256, 0, stream>>>(
            nullptr, nullptr, nullptr, (unsigned*)d_out, nullptr, wo_hi, wo_lo, nullptr,
            b_out, nullptr, Tp, NTOK, CDIM, CDIM, 0, 0);

        gemm_b3<2, 1, false, true><<<dim3(3, 1568), 256, 0, stream>>>(
            nullptr, nullptr, nullptr, Tp, nullptr, wo_hi, wo_lo, nullptr,
            b_out, (float*)d_out, nullptr, NTOK, CDIM, CDIM, 0, 0);
    }
}

// Round 12
// 1519.777 us; speedup vs baseline: 1.3346x; 1.3346x over previous
//
#include <hip/hip_runtime.h>
#include <math.h>

#define NTOK 200704          // B*S = 4096*49
#define CDIM 384
#define NH3  1152            // 3*C
#define NHEADS 12
#define HD   32
#define SEQ  49
#define QL   77070336ULL     // CDIM*NTOK (one third of T)

typedef __attribute__((ext_vector_type(8))) short short8;
typedef __attribute__((ext_vector_type(4))) float f32x4;
typedef __attribute__((ext_vector_type(16))) float f32x16;

__device__ __forceinline__ float gelu_exact(float x) {
    return 0.5f * x * (1.0f + erff(x * 0.70710678118654752f));
}
__device__ __forceinline__ unsigned bf16rn_bits(float x) {
    unsigned u = __float_as_uint(x);
    return (u + 0x7fffu + ((u >> 16) & 1u)) & 0xffff0000u;
}
__device__ __forceinline__ unsigned packsplit(float x) {
    unsigned hb = bf16rn_bits(x);
    float r = x - __uint_as_float(hb);
    unsigned lb = bf16rn_bits(r);
    return hb | (lb >> 16);
}
__device__ __forceinline__ void gl_lds16(const void* g, void* l) {
    __builtin_amdgcn_global_load_lds((const __attribute__((address_space(1))) void*)g,
                                     (__attribute__((address_space(3))) void*)l, 16, 0, 0);
}
union F8 { short8 v; unsigned u[4]; };
__device__ __forceinline__ void unpack8(uint4 a, uint4 b, short8 &h, short8 &l) {
    F8 H, L;
    H.u[0] = __builtin_amdgcn_perm(a.y, a.x, 0x07060302u);
    H.u[1] = __builtin_amdgcn_perm(a.w, a.z, 0x07060302u);
    H.u[2] = __builtin_amdgcn_perm(b.y, b.x, 0x07060302u);
    H.u[3] = __builtin_amdgcn_perm(b.w, b.z, 0x07060302u);
    L.u[0] = __builtin_amdgcn_perm(a.y, a.x, 0x05040100u);
    L.u[1] = __builtin_amdgcn_perm(a.w, a.z, 0x05040100u);
    L.u[2] = __builtin_amdgcn_perm(b.y, b.x, 0x05040100u);
    L.u[3] = __builtin_amdgcn_perm(b.w, b.z, 0x05040100u);
    h = H.v; l = L.v;
}

// ---------------------------------------------------------------------------
// prep_w: w (Kdim x Mdim row-major fp32) -> hi/lo bf16 granules [koct][Mdim][8]
// ---------------------------------------------------------------------------
__global__ __launch_bounds__(256)
void prep_w(const float* __restrict__ w, unsigned short* __restrict__ hi,
            unsigned short* __restrict__ lo, int Mdim, int Kdim) {
    int idx = blockIdx.x * 256 + threadIdx.x;
    int total = Mdim * (Kdim >> 3);
    if (idx >= total) return;
    int koct = idx / Mdim, m = idx - koct * Mdim;
    unsigned short h8[8], l8[8];
    #pragma unroll
    for (int j = 0; j < 8; ++j) {
        float v = w[(size_t)(koct * 8 + j) * Mdim + m];
        unsigned hb = bf16rn_bits(v);
        h8[j] = (unsigned short)(hb >> 16);
        l8[j] = (unsigned short)(bf16rn_bits(v - __uint_as_float(hb)) >> 16);
    }
    size_t o = (size_t)idx * 8;
    *(short8*)&hi[o] = *(short8*)h8;
    *(short8*)&lo[o] = *(short8*)l8;
}

// prep_x: fp32 row-major -> packed-split u32, same layout
__global__ __launch_bounds__(256)
void prep_x(const float* __restrict__ x, unsigned* __restrict__ xp, int total8) {
    int idx = blockIdx.x * 256 + threadIdx.x;
    if (idx >= total8) return;
    size_t e = (size_t)idx * 8;
    float4 v0 = *(const float4*)&x[e];
    float4 v1 = *(const float4*)&x[e + 4];
    *(uint4*)&xp[e]     = make_uint4(packsplit(v0.x), packsplit(v0.y), packsplit(v0.z), packsplit(v0.w));
    *(uint4*)&xp[e + 4] = make_uint4(packsplit(v1.x), packsplit(v1.y), packsplit(v1.z), packsplit(v1.w));
}

// ---------------------------------------------------------------------------
// bf16x3 GEMM, 128x128 tile, BK=32, 4 waves (2x2 of 64x64), single-buffered
// LDS, MFMA 32x32x16. (R8-proven structure)
// ---------------------------------------------------------------------------
template<int AMODE, int BMODE, bool BIAS_ROW, bool OUTF>
__global__ __launch_bounds__(256, 4)
void gemm_b3(const float* __restrict__ Af,
             const unsigned short* __restrict__ Agh, const unsigned short* __restrict__ Agl,
             const unsigned* __restrict__ Ap,
             const float* __restrict__ Bf,
             const unsigned short* __restrict__ Bgh, const unsigned short* __restrict__ Bgl,
             const unsigned* __restrict__ Bp,
             const float* __restrict__ bias, float* __restrict__ outF,
             unsigned* __restrict__ outP,
             int M, int N, int K, int nMt, int cpx) {
    __shared__ char smA[16384];
    __shared__ char smB[16384];
    const int tid = threadIdx.x;
    int m0, n0;
    if (cpx > 0) {  // XCD-chunked 1D grid: consecutive wg share the token tile
        int wg = (blockIdx.x & 7) * cpx + (blockIdx.x >> 3);
        m0 = (wg % nMt) * 128;
        n0 = (wg / nMt) * 128;
    } else {
        n0 = blockIdx.x * 128;
        m0 = blockIdx.y * 128;
    }
    const int wid = tid >> 6, lane = tid & 63;
    const int wm = wid >> 1, wn = wid & 1;
    const int l31 = lane & 31, lh = lane >> 5;
    const int f_r = tid >> 3, f_f4 = tid & 7;
    const int f_qq = f_f4 >> 1, f_half = (f_f4 & 1) * 8;

    unsigned short* BhT = (unsigned short*)smB;
    unsigned short* BlT = (unsigned short*)(smB + 8192);

    f32x16 acc[2][2] = {};

    for (int k0 = 0; k0 < K; k0 += 32) {
        const int kb = k0 >> 3;
        if constexpr (AMODE == 1) {
            #pragma unroll
            for (int it = 0; it < 2; ++it) {
                int g = it * 256 + tid;
                int qq = g >> 7, r = g & 127;
                size_t src = ((size_t)(kb + qq) * M + m0 + r) * 8;
                gl_lds16(Agh + src, smA + g * 16);
                gl_lds16(Agl + src, smA + 8192 + g * 16);
            }
        } else if constexpr (AMODE == 2) {
            #pragma unroll
            for (int it = 0; it < 4; ++it) {
                int row = it * 32 + (tid >> 3);
                int slot = (tid & 7) ^ (row & 7);
                gl_lds16(Ap + (size_t)(m0 + row) * K + k0 + slot * 4,
                         smA + (size_t)(it * 256 + tid) * 16);
            }
        }
        if constexpr (BMODE == 1) {
            #pragma unroll
            for (int it = 0; it < 2; ++it) {
                int g = it * 256 + tid;
                int qq = g >> 7, r = g & 127;
                size_t src = ((size_t)(kb + qq) * N + n0 + r) * 8;
                gl_lds16(Bgh + src, smB + g * 16);
                gl_lds16(Bgl + src, smB + 8192 + g * 16);
            }
        } else if constexpr (BMODE == 2) {
            #pragma unroll
            for (int it = 0; it < 4; ++it) {
                int row = it * 32 + (tid >> 3);
                int slot = (tid & 7) ^ (row & 7);
                gl_lds16(Bp + (size_t)(n0 + row) * K + k0 + slot * 4,
                         smB + (size_t)(it * 256 + tid) * 16);
            }
        } else {
            #pragma unroll
            for (int it = 0; it < 4; ++it) {
                int r = it * 32 + f_r;
                float4 v = *(const float4*)&Bf[(size_t)(n0 + r) * K + k0 + f_f4 * 4];
                unsigned hb0 = bf16rn_bits(v.x), hb1 = bf16rn_bits(v.y);
                unsigned hb2 = bf16rn_bits(v.z), hb3 = bf16rn_bits(v.w);
                unsigned l0 = bf16rn_bits(v.x - __uint_as_float(hb0)) >> 16;
                unsigned l1 = bf16rn_bits(v.y - __uint_as_float(hb1)) >> 16;
                unsigned l2 = bf16rn_bits(v.z - __uint_as_float(hb2)) >> 16;
                unsigned l3 = bf16rn_bits(v.w - __uint_as_float(hb3)) >> 16;
                unsigned h0 = hb0 >> 16, h1 = hb1 >> 16, h2 = hb2 >> 16, h3 = hb3 >> 16;
                *(uint2*)((char*)(BhT + (f_qq * 128 + r) * 8) + f_half) =
                    make_uint2(h0 | (h1 << 16), h2 | (h3 << 16));
                *(uint2*)((char*)(BlT + (f_qq * 128 + r) * 8) + f_half) =
                    make_uint2(l0 | (l1 << 16), l2 | (l3 << 16));
            }
        }
        __syncthreads();

        short8 ah[2][2], al[2][2], bh[2][2], bl[2][2];
        #pragma unroll
        for (int mi = 0; mi < 2; ++mi) {
            int r = wm * 64 + mi * 32 + l31;
            #pragma unroll
            for (int ko = 0; ko < 2; ++ko) {
                int o = 2 * ko + lh;
                if constexpr (AMODE == 2) {
                    int s0 = (2 * o) ^ (r & 7), s1 = s0 ^ 1;
                    const unsigned* base = (const unsigned*)smA + r * 32;
                    uint4 a = *(const uint4*)(base + s0 * 4);
                    uint4 b = *(const uint4*)(base + s1 * 4);
                    unpack8(a, b, ah[mi][ko], al[mi][ko]);
                } else {
                    ah[mi][ko] = *(const short8*)((const unsigned short*)smA + (o * 128 + r) * 8);
                    al[mi][ko] = *(const short8*)((const unsigned short*)(smA + 8192) + (o * 128 + r) * 8);
                }
            }
        }
        #pragma unroll
        for (int ni = 0; ni < 2; ++ni) {
            int r = wn * 64 + ni * 32 + l31;
            #pragma unroll
            for (int ko = 0; ko < 2; ++ko) {
                int o = 2 * ko + lh;
                if constexpr (BMODE == 2) {
                    int s0 = (2 * o) ^ (r & 7), s1 = s0 ^ 1;
                    const unsigned* base = (const unsigned*)smB + r * 32;
                    uint4 a = *(const uint4*)(base + s0 * 4);
                    uint4 b = *(const uint4*)(base + s1 * 4);
                    unpack8(a, b, bh[ni][ko], bl[ni][ko]);
                } else {
                    bh[ni][ko] = *(const short8*)(BhT + (o * 128 + r) * 8);
                    bl[ni][ko] = *(const short8*)(BlT + (o * 128 + r) * 8);
                }
            }
        }
        #pragma unroll
        for (int ko = 0; ko < 2; ++ko)
            #pragma unroll
            for (int mi = 0; mi < 2; ++mi)
                #pragma unroll
                for (int ni = 0; ni < 2; ++ni) {
                    acc[mi][ni] = __builtin_amdgcn_mfma_f32_32x32x16_bf16(ah[mi][ko], bh[ni][ko], acc[mi][ni], 0, 0, 0);
                    acc[mi][ni] = __builtin_amdgcn_mfma_f32_32x32x16_bf16(ah[mi][ko], bl[ni][ko], acc[mi][ni], 0, 0, 0);
                    acc[mi][ni] = __builtin_amdgcn_mfma_f32_32x32x16_bf16(al[mi][ko], bh[ni][ko], acc[mi][ni], 0, 0, 0);
                }
        __syncthreads();
    }

    #pragma unroll
    for (int mi = 0; mi < 2; ++mi) {
        #pragma unroll
        for (int ni = 0; ni < 2; ++ni) {
            int gc = n0 + wn * 64 + ni * 32 + l31;
            #pragma unroll
            for (int reg = 0; reg < 16; ++reg) {
                int gr = m0 + wm * 64 + mi * 32 + (reg & 3) + 8 * (reg >> 2) + 4 * lh;
                float b = BIAS_ROW ? bias[gr] : bias[gc];
                float v = gelu_exact(acc[mi][ni][reg] + b);
                if constexpr (OUTF) outF[(size_t)gr * N + gc] = v;
                else                outP[(size_t)gr * N + gc] = packsplit(v);
            }
        }
    }
}

// ---------------------------------------------------------------------------
// MFMA attention (R10-proven): one wave per (window, head), no block
// barriers (wave-private LDS), b64 V^T staging.
// ---------------------------------------------------------------------------
__global__ __launch_bounds__(256, 2)
void attn_mfma(const unsigned* __restrict__ Tp, const float* __restrict__ bias_table,
               unsigned* __restrict__ Yp) {
    __shared__ unsigned short Vh[4][32][72];
    __shared__ unsigned short Vl[4][32][72];
    __shared__ unsigned PHs[4][16][36];
    __shared__ unsigned PLs[4][16][36];

    const int tid = threadIdx.x, wid = tid >> 6, lane = tid & 63;
    const int pidx = blockIdx.x * 4 + wid;
    const int b2 = pidx / NHEADS, h = pidx - b2 * NHEADS;
    const size_t qoff = (size_t)b2 * 18816 + (size_t)h * 1568;
    const int r15 = lane & 15, g = lane >> 4;

    #pragma unroll
    for (int it = 0; it < 2; ++it) {
        const int dq = lane & 7;
        const int tq = (lane >> 3) + it * 8;
        uint4 p[4];
        #pragma unroll
        for (int u = 0; u < 4; ++u) {
            int t = tq * 4 + u; if (t > 48) t = 48;
            p[u] = *(const uint4*)&Tp[2 * QL + qoff + (size_t)t * HD + dq * 4];
        }
        #pragma unroll
        for (int c = 0; c < 4; ++c) {
            unsigned q0 = (c == 0) ? p[0].x : (c == 1) ? p[0].y : (c == 2) ? p[0].z : p[0].w;
            unsigned q1 = (c == 0) ? p[1].x : (c == 1) ? p[1].y : (c == 2) ? p[1].z : p[1].w;
            unsigned q2 = (c == 0) ? p[2].x : (c == 1) ? p[2].y : (c == 2) ? p[2].z : p[2].w;
            unsigned q3 = (c == 0) ? p[3].x : (c == 1) ? p[3].y : (c == 2) ? p[3].z : p[3].w;
            unsigned hw0 = __builtin_amdgcn_perm(q1, q0, 0x07060302u);
            unsigned hw1 = __builtin_amdgcn_perm(q3, q2, 0x07060302u);
            unsigned lw0 = __builtin_amdgcn_perm(q1, q0, 0x05040100u);
            unsigned lw1 = __builtin_amdgcn_perm(q3, q2, 0x05040100u);
            *(uint2*)&Vh[wid][dq * 4 + c][tq * 4] = make_uint2(hw0, hw1);
            *(uint2*)&Vl[wid][dq * 4 + c][tq * 4] = make_uint2(lw0, lw1);
        }
    }

    f32x4 S[4][4];
    int cS[4];
    #pragma unroll
    for (int st = 0; st < 4; ++st) {
        int s = st * 16 + r15; if (s > 48) s = 48;
        int sd = (s * 37) >> 8;
        cS[st] = 156 * (12 - (s - 6 * sd)) + h;
    }
    #pragma unroll
    for (int tt = 0; tt < 4; ++tt)
        #pragma unroll
        for (int r = 0; r < 4; ++r) {
            int t = tt * 16 + 4 * g + r; int tc2 = t > 48 ? 48 : t;
            int td = (tc2 * 37) >> 8;
            int at = 156 * (tc2 - 6 * td);
            #pragma unroll
            for (int st = 0; st < 4; ++st)
                S[tt][st][r] = bias_table[at + cS[st]];
        }

    short8 qh[4], qlo[4];
    #pragma unroll
    for (int st = 0; st < 4; ++st) {
        int s = st * 16 + r15; if (s > 48) s = 48;
        const unsigned* p = Tp + qoff + (size_t)s * HD + g * 8;
        uint4 a = *(const uint4*)p;
        uint4 b = *(const uint4*)(p + 4);
        unpack8(a, b, qh[st], qlo[st]);
    }
    #pragma unroll
    for (int tt = 0; tt < 4; ++tt) {
        int t = tt * 16 + r15; if (t > 48) t = 48;
        const unsigned* p = Tp + QL + qoff + (size_t)t * HD + g * 8;
        uint4 a = *(const uint4*)p;
        uint4 b = *(const uint4*)(p + 4);
        short8 kh, kl; unpack8(a, b, kh, kl);
        #pragma unroll
        for (int st = 0; st < 4; ++st) {
            S[tt][st] = __builtin_amdgcn_mfma_f32_16x16x32_bf16(kh, qh[st],  S[tt][st], 0, 0, 0);
            S[tt][st] = __builtin_amdgcn_mfma_f32_16x16x32_bf16(kh, qlo[st], S[tt][st], 0, 0, 0);
            S[tt][st] = __builtin_amdgcn_mfma_f32_16x16x32_bf16(kl, qh[st],  S[tt][st], 0, 0, 0);
        }
    }
    #pragma unroll
    for (int st = 0; st < 4; ++st) {
        S[3][st][0] = (g == 0) ? S[3][st][0] : -1e30f;
        S[3][st][1] = -1e30f; S[3][st][2] = -1e30f; S[3][st][3] = -1e30f;
    }
    float inv[4];
    #pragma unroll
    for (int st = 0; st < 4; ++st) {
        float mx = -1e30f;
        #pragma unroll
        for (int tt = 0; tt < 4; ++tt)
            #pragma unroll
            for (int r = 0; r < 4; ++r) mx = fmaxf(mx, S[tt][st][r]);
        mx = fmaxf(mx, __shfl_xor(mx, 16));
        mx = fmaxf(mx, __shfl_xor(mx, 32));
        float sm = 0.f;
        #pragma unroll
        for (int tt = 0; tt < 4; ++tt)
            #pragma unroll
            for (int r = 0; r < 4; ++r) {
                float e = __expf(S[tt][st][r] - mx);
                S[tt][st][r] = e; sm += e;
            }
        sm += __shfl_xor(sm, 16);
        sm += __shfl_xor(sm, 32);
        inv[st] = 1.0f / sm;
    }
    short8 vfh[2][2], vfl[2][2];
    #pragma unroll
    for (int dt = 0; dt < 2; ++dt)
        #pragma unroll
        for (int kc = 0; kc < 2; ++kc) {
            int d = dt * 16 + r15;
            vfh[dt][kc] = *(const short8*)&Vh[wid][d][kc * 32 + g * 8];
            vfl[dt][kc] = *(const short8*)&Vl[wid][d][kc * 32 + g * 8];
        }
    for (int st = 0; st < 4; ++st) {
        #pragma unroll
        for (int tt = 0; tt < 4; ++tt)
            #pragma unroll
            for (int rp = 0; rp < 2; ++rp) {
                float p0 = S[tt][st][2 * rp]     * inv[st];
                float p1 = S[tt][st][2 * rp + 1] * inv[st];
                unsigned h0 = bf16rn_bits(p0), h1 = bf16rn_bits(p1);
                unsigned l0 = bf16rn_bits(p0 - __uint_as_float(h0));
                unsigned l1 = bf16rn_bits(p1 - __uint_as_float(h1));
                int w = tt * 8 + 2 * g + rp;
                int wsw = (((w >> 2) ^ (r15 & 7)) << 2) + (w & 3);
                PHs[wid][r15][wsw] = __builtin_amdgcn_perm(h1, h0, 0x07060302u);
                PLs[wid][r15][wsw] = __builtin_amdgcn_perm(l1, l0, 0x07060302u);
            }
        f32x4 o[2] = {};
        #pragma unroll
        for (int kc = 0; kc < 2; ++kc) {
            int grp = (4 * kc + g) ^ (r15 & 7);
            short8 ph = *(const short8*)&PHs[wid][r15][grp * 4];
            short8 pl = *(const short8*)&PLs[wid][r15][grp * 4];
            #pragma unroll
            for (int dt = 0; dt < 2; ++dt) {
                o[dt] = __builtin_amdgcn_mfma_f32_16x16x32_bf16(ph, vfh[dt][kc], o[dt], 0, 0, 0);
                o[dt] = __builtin_amdgcn_mfma_f32_16x16x32_bf16(ph, vfl[dt][kc], o[dt], 0, 0, 0);
                o[dt] = __builtin_amdgcn_mfma_f32_16x16x32_bf16(pl, vfh[dt][kc], o[dt], 0, 0, 0);
            }
        }
        #pragma unroll
        for (int r = 0; r < 4; ++r) {
            int s = st * 16 + 4 * g + r;
            if (s < SEQ) {
                size_t ob = ((size_t)b2 * SEQ + s) * CDIM + h * HD + r15;
                Yp[ob]      = packsplit(o[0][r]);
                Yp[ob + 16] = packsplit(o[1][r]);
            }
        }
    }
}

extern "C" void kernel_launch(void* const* d_in, const int* in_sizes, int n_in,
                              void* d_out, int out_size, void* d_ws, size_t ws_size,
                              hipStream_t stream) {
    const float* x          = (const float*)d_in[0];
    const float* w_qkv      = (const float*)d_in[1];
    const float* b_qkv      = (const float*)d_in[2];
    const float* bias_table = (const float*)d_in[3];
    const float* w_out      = (const float*)d_in[4];
    const float* b_out      = (const float*)d_in[5];
    unsigned* Tp = (unsigned*)d_ws;
    const size_t TPW = 3 * QL;

    const size_t need = TPW * 4ULL + (size_t)NH3 * CDIM * 4ULL + (size_t)CDIM * CDIM * 4ULL;

    if (ws_size >= need) {
        unsigned short* wq_hi = (unsigned short*)((char*)d_ws + TPW * 4ULL);
        unsigned short* wq_lo = wq_hi + (size_t)NH3 * CDIM;
        unsigned short* wo_hi = wq_lo + (size_t)NH3 * CDIM;
        unsigned short* wo_lo = wo_hi + (size_t)CDIM * CDIM;
        unsigned* xp = (unsigned*)d_out;

        prep_w<<<(NH3 * 48 + 255) / 256, 256, 0, stream>>>(w_qkv, wq_hi, wq_lo, NH3, CDIM);
        prep_w<<<(CDIM * 48 + 255) / 256, 256, 0, stream>>>(w_out, wo_hi, wo_lo, CDIM, CDIM);
        prep_x<<<(NTOK * CDIM / 8 + 255) / 256, 256, 0, stream>>>(x, xp, NTOK * CDIM / 8);

        gemm_b3<1, 2, true, false><<<14112, 256, 0, stream>>>(
            nullptr, wq_hi, wq_lo, nullptr, nullptr, nullptr, nullptr, xp,
            b_qkv, nullptr, Tp, NH3, NTOK, CDIM, 9, 1764);

        attn_mfma<<<12288, 256, 0, stream>>>(Tp, bias_table, (unsigned*)d_out);

        gemm_b3<2, 1, false, false><<<dim3(3, 1568), 256, 0, stream>>>(
            nullptr, nullptr, nullptr, (unsigned*)d_out, nullptr, wo_hi, wo_lo, nullptr,
            b_out, nullptr, Tp, NTOK, CDIM, CDIM, 0, 0);

        gemm_b3<2, 1, false, true><<<dim3(3, 1568), 256, 0, stream>>>(
            nullptr, nullptr, nullptr, Tp, nullptr, wo_hi, wo_lo, nullptr,
            b_out, (float*)d_out, nullptr, NTOK, CDIM, CDIM, 0, 0);
    } else {
        // fallback: weights in d_out / dead T third; x staged fp32 inline
        unsigned short* wq_hi = (unsigned short*)d_out;
        unsigned short* wq_lo = wq_hi + (size_t)NH3 * CDIM;
        unsigned short* wo_hi = (unsigned short*)(Tp + QL);
        unsigned short* wo_lo = wo_hi + (size_t)CDIM * CDIM;

        prep_w<<<(NH3 * 48 + 255) / 256, 256, 0, stream>>>(w_qkv, wq_hi, wq_lo, NH3, CDIM);

        gemm_b3<1, 0, true, false><<<14112, 256, 0, stream>>>(
            nullptr, wq_hi, wq_lo, nullptr, x, nullptr, nullptr, nullptr,
            b_qkv, nullptr, Tp, NH3, NTOK, CDIM, 9, 1764);

        attn_mfma<<<12288, 256, 0, stream>>>(Tp, bias_table, (unsigned*)d_out);

        prep_w<<<(CDIM * 48 + 255) / 256, 256, 0, stream>>>(w_out, wo_hi, wo_lo, CDIM, CDIM);

        gemm_b3<2, 1, false, false><<<dim3(3, 1568), 256, 0, stream>>>(
            nullptr, nullptr, nullptr, (unsigned*)d_out, nullptr, wo_hi, wo_lo, nullptr,
            b_out, nullptr, Tp, NTOK, CDIM, CDIM, 0, 0);

        gemm_b3<2, 1, false, true><<<dim3(3, 1568), 256, 0, stream>>>(
            nullptr, nullptr, nullptr, Tp, nullptr, wo_hi, wo_lo, nullptr,
            b_out, (float*)d_out, nullptr, NTOK, CDIM, CDIM, 0, 0);
    }
}